// Round 8
// baseline (1129.584 us; speedup 1.0000x reference)
//
#include <hip/hip_runtime.h>
#include <hip/hip_bf16.h>
#include <math.h>

#define N_NODES 50000
#define N_EDGES 800000
#define NH 4
#define DH 32
#define IN_DIM 256
#define OUTC 160
#define LS 570400     // int(0.713 * 800000) -> exactly 570400
#define RANK0 (LS - 1)
#define DEG_CAP 160   // max in-degree supported (Poisson(16); 160 = ~36 sigma)

typedef unsigned long long u64;
#define SC_FX 1099511627776.0   // 2^40 fixed-point scale

// ======== CSR build (A doubles as deg, cursor, and post-fill offsets[i+1]) ========
__global__ void k_deg(const int* __restrict__ dst, unsigned* __restrict__ A){
  int e = blockIdx.x * 256 + threadIdx.x;
  if (e < N_EDGES) atomicAdd(&A[dst[e]], 1u);
}

__global__ __launch_bounds__(1024) void k_scan(unsigned* __restrict__ A){
  __shared__ unsigned ps[1024];
  int t = threadIdx.x;
  const int CH = (N_NODES + 1023) / 1024;
  int base = t * CH;
  unsigned s = 0;
  for (int i = 0; i < CH; i++){ int n = base + i; if (n < N_NODES) s += A[n]; }
  ps[t] = s;
  __syncthreads();
  for (int off = 1; off < 1024; off <<= 1){
    unsigned v = (t >= off) ? ps[t - off] : 0;
    __syncthreads();
    ps[t] += v;
    __syncthreads();
  }
  unsigned ex = (t == 0) ? 0 : ps[t - 1];
  for (int i = 0; i < CH; i++){
    int n = base + i;
    if (n < N_NODES){ unsigned dv = A[n]; A[n] = ex; ex += dv; }
  }
}

__global__ void k_fill(const int* __restrict__ dst, unsigned* __restrict__ A,
                       unsigned* __restrict__ eidx){
  int e = blockIdx.x * 256 + threadIdx.x;
  if (e < N_EDGES) eidx[atomicAdd(&A[dst[e]], 1u)] = (unsigned)e;
}
// post-fill: A[d] == offsets[d+1]; node d range = [d? A[d-1]:0, A[d])

__global__ void k_init(u64* __restrict__ sel4, unsigned* __restrict__ krem,
                       unsigned* __restrict__ cnt, unsigned* __restrict__ done,
                       unsigned* __restrict__ ccnt, u64* __restrict__ gsums){
  int t = threadIdx.x;
  if (t < 4){ sel4[t] = 0; krem[t] = RANK0; cnt[t] = 0; ccnt[t] = 0; }
  if (t < 8) gsums[t] = 0;
  if (t == 0) done[0] = 0;
}

// ======== fp32 GEMM: ft32 = h * Wl^T ========
#define BM 128
#define BK 16
__global__ __launch_bounds__(256) void k_gemm32(const float* __restrict__ A,
                                                const float* __restrict__ Wl,
                                                float* __restrict__ C){
  __shared__ float As[BK][BM + 4];
  __shared__ float Bs[BK][128 + 4];
  int tid = threadIdx.x;
  int m0 = blockIdx.x * BM;
  int ty = tid / 16, tx = tid % 16;
  float acc[8][8];
  #pragma unroll
  for (int i = 0; i < 8; i++)
    #pragma unroll
    for (int j = 0; j < 8; j++) acc[i][j] = 0.f;

  for (int k0 = 0; k0 < IN_DIM; k0 += BK){
    #pragma unroll
    for (int i = 0; i < 2; i++){
      int s = tid * 2 + i;
      int row = s >> 2, c4 = s & 3;
      int r = m0 + row;
      float4 v = make_float4(0.f, 0.f, 0.f, 0.f);
      if (r < N_NODES) v = *(const float4*)&A[(size_t)r * IN_DIM + k0 + c4 * 4];
      As[c4 * 4 + 0][row] = v.x; As[c4 * 4 + 1][row] = v.y;
      As[c4 * 4 + 2][row] = v.z; As[c4 * 4 + 3][row] = v.w;
    }
    #pragma unroll
    for (int i = 0; i < 2; i++){
      int s = tid * 2 + i;
      int j = s >> 2, c4 = s & 3;          // Bs[k][j] = Wl[j][k0+k]
      float4 v = *(const float4*)&Wl[(size_t)j * IN_DIM + k0 + c4 * 4];
      Bs[c4 * 4 + 0][j] = v.x; Bs[c4 * 4 + 1][j] = v.y;
      Bs[c4 * 4 + 2][j] = v.z; Bs[c4 * 4 + 3][j] = v.w;
    }
    __syncthreads();
    #pragma unroll
    for (int kk = 0; kk < BK; kk++){
      float4 a0 = *(const float4*)&As[kk][ty * 4];
      float4 a1 = *(const float4*)&As[kk][64 + ty * 4];
      float4 b0 = *(const float4*)&Bs[kk][tx * 4];
      float4 b1 = *(const float4*)&Bs[kk][64 + tx * 4];
      float av[8] = {a0.x, a0.y, a0.z, a0.w, a1.x, a1.y, a1.z, a1.w};
      float bv[8] = {b0.x, b0.y, b0.z, b0.w, b1.x, b1.y, b1.z, b1.w};
      #pragma unroll
      for (int i = 0; i < 8; i++)
        #pragma unroll
        for (int j = 0; j < 8; j++)
          acc[i][j] = fmaf(av[i], bv[j], acc[i][j]);
    }
    __syncthreads();
  }
  #pragma unroll
  for (int i = 0; i < 8; i++){
    int r = m0 + ((i < 4) ? (ty * 4 + i) : (64 + ty * 4 + (i - 4)));
    if (r >= N_NODES) continue;
    *(float4*)&C[(size_t)r * 128 + tx * 4]      = make_float4(acc[i][0], acc[i][1], acc[i][2], acc[i][3]);
    *(float4*)&C[(size_t)r * 128 + 64 + tx * 4] = make_float4(acc[i][4], acc[i][5], acc[i][6], acc[i][7]);
  }
}

// ======== fp64 GEMM -> separate c64/q64 tables ========
__global__ __launch_bounds__(256) void k_gemm64(const float* __restrict__ A,
                                                const float* __restrict__ fc,
                                                const float* __restrict__ fq,
                                                double* __restrict__ c64,
                                                double* __restrict__ q64){
  __shared__ double As[16][66];
  __shared__ double Bs[16][66];
  int tid = threadIdx.x;
  int m0 = blockIdx.x * 64;
  int n0 = blockIdx.y * 64;                 // 0..255 over [fc | fq]
  const float* Bsrc = (n0 < 128) ? fc : fq;
  int j0 = (n0 < 128) ? n0 : n0 - 128;
  double* Cp = (n0 < 128) ? c64 : q64;
  int ty = tid / 16, tx = tid % 16;
  double acc[4][4];
  #pragma unroll
  for (int i = 0; i < 4; i++)
    #pragma unroll
    for (int j = 0; j < 4; j++) acc[i][j] = 0.0;

  for (int k0 = 0; k0 < IN_DIM; k0 += 16){
    {
      int row = tid >> 2, c4 = tid & 3;
      int r = m0 + row;
      float4 v = make_float4(0.f, 0.f, 0.f, 0.f);
      if (r < N_NODES) v = *(const float4*)&A[(size_t)r * IN_DIM + k0 + c4 * 4];
      As[c4 * 4 + 0][row] = (double)v.x; As[c4 * 4 + 1][row] = (double)v.y;
      As[c4 * 4 + 2][row] = (double)v.z; As[c4 * 4 + 3][row] = (double)v.w;
    }
    {
      int kr = tid >> 4, c4 = tid & 15;
      float4 v = *(const float4*)&Bsrc[(size_t)(k0 + kr) * 128 + j0 + c4 * 4];
      Bs[kr][c4 * 4 + 0] = (double)v.x; Bs[kr][c4 * 4 + 1] = (double)v.y;
      Bs[kr][c4 * 4 + 2] = (double)v.z; Bs[kr][c4 * 4 + 3] = (double)v.w;
    }
    __syncthreads();
    #pragma unroll
    for (int kk = 0; kk < 16; kk++){
      double a[4], b[4];
      #pragma unroll
      for (int i = 0; i < 4; i++) a[i] = As[kk][ty * 4 + i];
      #pragma unroll
      for (int j = 0; j < 4; j++) b[j] = Bs[kk][tx * 4 + j];
      #pragma unroll
      for (int i = 0; i < 4; i++)
        #pragma unroll
        for (int j = 0; j < 4; j++)
          acc[i][j] = fma(a[i], b[j], acc[i][j]);
    }
    __syncthreads();
  }
  #pragma unroll
  for (int i = 0; i < 4; i++){
    int r = m0 + ty * 4 + i;
    if (r >= N_NODES) continue;
    double* p = &Cp[(size_t)r * 128 + j0 + tx * 4];
    *(double2*)p       = make_double2(acc[i][0], acc[i][1]);
    *(double2*)(p + 2) = make_double2(acc[i][2], acc[i][3]);
  }
}

// ======== fused edge logits + exact softmax (wave per dst, CSR order) ========
__global__ __launch_bounds__(256) void k_softedge(const double* __restrict__ c64,
    const double* __restrict__ q64, const int* __restrict__ src,
    const unsigned* __restrict__ A, const unsigned* __restrict__ eidx,
    double* __restrict__ abuf){
  __shared__ double lds_a[4][DEG_CAP * 4];
  int d = blockIdx.x * 4 + (threadIdx.x >> 6);
  int t = threadIdx.x & 63;
  int wv = threadIdx.x >> 6;
  if (d >= N_NODES) return;
  unsigned k0 = d ? A[d - 1] : 0u, k1 = A[d];
  if (k0 == k1) return;
  double2 c = *(const double2*)&c64[(size_t)d * 128 + t * 2];
  double m = -1.0e300;
  int sn = src[eidx[k0]];
  double2 qn = *(const double2*)&q64[(size_t)sn * 128 + t * 2];
  for (unsigned k = k0; k < k1; k++){
    double2 q = qn;
    if (k + 1 < k1){
      int s2 = src[eidx[k + 1]];
      qn = *(const double2*)&q64[(size_t)s2 * 128 + t * 2];
    }
    double val = (q.x - c.x) * c.x + (q.y - c.y) * c.y;
    val += __shfl_xor(val, 1);
    val += __shfl_xor(val, 2);
    val += __shfl_xor(val, 4);
    val += __shfl_xor(val, 8);
    double a = (val > 0.0) ? val : expm1(val);   // ELU (f64)
    m = fmax(m, a);
    if ((t & 15) == 0) lds_a[wv][(k - k0) * 4 + (t >> 4)] = a;
  }
  double mm = __shfl(m, (t & 3) * 16);
  unsigned nj = (k1 - k0) * 4;
  long long sfx = 0;
  for (unsigned jj = t; jj < nj; jj += 64){
    double ex = exp(lds_a[wv][jj] - mm);         // jj%4 == t%4 (64%4==0)
    lds_a[wv][jj] = ex;
    sfx += llrint(ex * SC_FX);
  }
  #pragma unroll
  for (int msk = 4; msk < 64; msk <<= 1) sfx += __shfl_xor(sfx, msk);
  double sd = (double)sfx * (1.0 / SC_FX);
  for (unsigned jj = t; jj < nj; jj += 64)
    abuf[(size_t)k0 * 4 + jj] = lds_a[wv][jj] / sd;
}

// ======== radix select: hist+pick fused (last-block ticket), full array ========
__global__ __launch_bounds__(256) void k_hp(const double* __restrict__ attn,
    u64* __restrict__ sel4, unsigned* __restrict__ krem, unsigned* __restrict__ cnt,
    unsigned* __restrict__ hist, unsigned* __restrict__ done, u64 maskHi, int shift){
  __shared__ unsigned lh[1024];
  __shared__ unsigned ticket;
  for (int j = threadIdx.x; j < 1024; j += 256) lh[j] = 0;
  __syncthreads();
  int i0 = blockIdx.x * 256 + threadIdx.x;
  int hh = i0 & 3;
  u64 sel = sel4[hh] & maskHi;
  const int total = N_EDGES * 4;
  for (int i = i0; i < total; i += gridDim.x * 256){
    u64 u = (u64)__double_as_longlong(attn[i]);
    if ((u & maskHi) == sel)
      atomicAdd(&lh[hh * 256 + (unsigned)((u >> shift) & 255u)], 1u);
  }
  __syncthreads();
  for (int j = threadIdx.x; j < 1024; j += 256)
    if (lh[j]) atomicAdd(&hist[j], lh[j]);
  __threadfence();
  if (threadIdx.x == 0) ticket = atomicAdd(done, 1u);
  __syncthreads();
  if (ticket == gridDim.x - 1){
    __threadfence();
    for (int j = threadIdx.x; j < 1024; j += 256){ lh[j] = hist[j]; hist[j] = 0; }
    __syncthreads();
    if (threadIdx.x < 4){
      int t = threadIdx.x;
      unsigned kr = krem[t], cum = 0, b = 0;
      for (; b < 256; b++){
        unsigned c2 = lh[t * 256 + b];
        if (kr < cum + c2) break;
        cum += c2;
      }
      sel4[t] |= ((u64)b) << shift;
      krem[t] = kr - cum;
      cnt[t] += cum;
    }
    if (threadIdx.x == 0) *done = 0;
  }
}

// ======== compact candidates matching top-16 bits (two-level allocation) ========
__global__ __launch_bounds__(256) void k_compact(const double* __restrict__ attn,
    const u64* __restrict__ sel4, unsigned* __restrict__ ccnt,
    double* __restrict__ cand){
  __shared__ unsigned lcnt[4];
  __shared__ unsigned lbase[4];
  int t = threadIdx.x;
  if (t < 4) lcnt[t] = 0;
  __syncthreads();
  int i0 = blockIdx.x * 256 + t;
  int hh = i0 & 3;
  u64 sel = sel4[hh] & 0xFFFF000000000000ull;
  const int total = N_EDGES * 4;
  unsigned mc = 0;
  for (int i = i0; i < total; i += gridDim.x * 256){
    u64 u = (u64)__double_as_longlong(attn[i]);
    if ((u & 0xFFFF000000000000ull) == sel) mc++;
  }
  unsigned my_local = mc ? atomicAdd(&lcnt[hh], mc) : 0u;
  __syncthreads();
  if (t < 4) lbase[t] = lcnt[t] ? atomicAdd(&ccnt[t], lcnt[t]) : 0u;
  __syncthreads();
  if (mc == 0) return;
  unsigned pos = lbase[hh] + my_local;
  double* cp = cand + (size_t)hh * N_EDGES;
  for (int i = i0; i < total; i += gridDim.x * 256){
    double v = attn[i];
    u64 u = (u64)__double_as_longlong(v);
    if ((u & 0xFFFF000000000000ull) == sel) cp[pos++] = v;
  }
}

// ======== one radix pass over compacted candidates (multi-block, ticket pick) ====
__global__ __launch_bounds__(256) void k_fin2(const double* __restrict__ cand,
    const unsigned* __restrict__ ccnt, u64* __restrict__ sel4,
    unsigned* __restrict__ krem, unsigned* __restrict__ cnt,
    unsigned* __restrict__ hist, unsigned* __restrict__ done, int shift){
  __shared__ unsigned lh[256];
  __shared__ unsigned ticket;
  int t = threadIdx.x;
  lh[t] = 0;
  __syncthreads();
  int h = blockIdx.x & 3;                    // 4-way head split
  int bidx = blockIdx.x >> 2;
  int bph = gridDim.x >> 2;                  // blocks per head
  u64 maskHi = ~((1ull << (shift + 8)) - 1);
  u64 sel = sel4[h] & maskHi;
  unsigned n = ccnt[h];
  const double* cp = cand + (size_t)h * N_EDGES;
  for (unsigned i = bidx * 256 + t; i < n; i += bph * 256){
    u64 u = (u64)__double_as_longlong(cp[i]);
    if ((u & maskHi) == sel) atomicAdd(&lh[(unsigned)((u >> shift) & 255u)], 1u);
  }
  __syncthreads();
  if (lh[t]) atomicAdd(&hist[h * 256 + t], lh[t]);
  __threadfence();
  if (t == 0) ticket = atomicAdd(done, 1u);
  __syncthreads();
  if (ticket == gridDim.x - 1){
    __threadfence();
    __shared__ unsigned fh[1024];
    for (int j = t; j < 1024; j += 256){ fh[j] = hist[j]; hist[j] = 0; }
    __syncthreads();
    if (t < 4){
      unsigned kr = krem[t], cum = 0, b = 0;
      for (; b < 256; b++){
        unsigned c2 = fh[t * 256 + b];
        if (kr < cum + c2) break;
        cum += c2;
      }
      sel4[t] |= ((u64)b) << shift;
      krem[t] = kr - cum;
      cnt[t] += cum;
    }
    if (t == 0) *done = 0;
  }
}

// ======== sums below/above thd + a3 (f32, exact-cut applied) ========
__global__ __launch_bounds__(256) void k_sums(const double* __restrict__ attn,
    const u64* __restrict__ sel4, u64* __restrict__ gsums, float* __restrict__ a3){
  int t = threadIdx.x;
  int i0 = blockIdx.x * 256 + t;
  int hh = t & 3;
  double thd = __longlong_as_double((long long)sel4[hh]);
  double al = 0.0, ag = 0.0;
  const int total = N_EDGES * 4;
  for (int i = i0; i < total; i += gridDim.x * 256){
    double v = attn[i];
    if (v < thd){ al += v; a3[i] = 0.f; }
    else        { ag += v; a3[i] = (float)v; }
  }
  long long ql = llrint(al * SC_FX);
  long long qg = llrint(ag * SC_FX);
  #pragma unroll
  for (int m = 4; m < 64; m <<= 1){
    ql += __shfl_xor(ql, m);
    qg += __shfl_xor(qg, m);
  }
  __shared__ long long sl[16], sg[16];
  int wv = t >> 6;
  if ((t & 63) < 4){ sl[wv * 4 + hh] = ql; sg[wv * 4 + hh] = qg; }
  __syncthreads();
  if (t < 4){
    long long a = sl[t] + sl[4 + t] + sl[8 + t] + sl[12 + t];
    long long b = sg[t] + sg[4 + t] + sg[8 + t] + sg[12 + t];
    if (a) atomicAdd(&gsums[t],     (u64)a);
    if (b) atomicAdd(&gsums[4 + t], (u64)b);
  }
}

__global__ void k_ratio(const u64* __restrict__ sel4, const unsigned* __restrict__ cnt,
                        const u64* __restrict__ gsums, double* __restrict__ trd){
  int t = threadIdx.x;
  if (t < 4){
    double thd = __longlong_as_double((long long)sel4[t]);
    double sless = (double)gsums[t]     * (1.0 / SC_FX);
    double sge   = (double)gsums[4 + t] * (1.0 / SC_FX);
    double topk  = sless + (double)(LS - (int)cnt[t]) * thd;
    trd[t] = thd;
    trd[4 + t] = (sge + topk) / sge;
  }
}

// ======== CSR gather-scatter (wave per dst, int64 fixed-point registers) ========
__global__ __launch_bounds__(256) void k_scatter2(const float* __restrict__ ft,
    const int* __restrict__ src, const unsigned* __restrict__ A,
    const unsigned* __restrict__ eidx, const float* __restrict__ a3,
    const double* __restrict__ trd, float* __restrict__ out){
  int d = blockIdx.x * 4 + (threadIdx.x >> 6);
  int t = threadIdx.x & 63;
  if (d >= N_NODES) return;
  int hh = t >> 4;
  double ratio = trd[4 + hh];
  unsigned k0 = d ? A[d - 1] : 0u, k1 = A[d];
  long long acc0 = 0, acc1 = 0;
  float wn = (k0 < k1) ? a3[(size_t)k0 * 4 + hh] : 0.f;
  unsigned en = (k0 < k1) ? eidx[k0] : 0u;
  for (unsigned k = k0; k < k1; k++){
    float w = wn;
    unsigned e = en;
    if (k + 1 < k1){ wn = a3[(size_t)(k + 1) * 4 + hh]; en = eidx[k + 1]; }
    if (__ballot(w != 0.f) == 0ull) continue;    // ~71% of edges dropped
    if (w != 0.f){
      int s = src[e];
      float2 f = *(const float2*)&ft[(size_t)s * 128 + t * 2];
      double a3r = (double)w * ratio;
      acc0 += llrint(a3r * (double)f.x * SC_FX);
      acc1 += llrint(a3r * (double)f.y * SC_FX);
    }
  }
  float* p = &out[(size_t)d * OUTC + t * 2];
  p[0] = (float)((double)acc0 * (1.0 / SC_FX));
  p[1] = (float)((double)acc1 * (1.0 / SC_FX));
}

// ======== head-mean (runs last) ========
__global__ void k_mean(const float* __restrict__ ft, float* __restrict__ out){
  int i = blockIdx.x * 256 + threadIdx.x;
  if (i >= N_NODES * DH) return;
  int n = i / DH, dd = i % DH;
  const float* p = ft + (size_t)n * 128;
  out[(size_t)n * OUTC + 128 + dd] = 0.25f * (p[dd] + p[32 + dd] + p[64 + dd] + p[96 + dd]);
}

extern "C" void kernel_launch(void* const* d_in, const int* in_sizes, int n_in,
                              void* d_out, int out_size, void* d_ws, size_t ws_size,
                              hipStream_t stream){
  const float* h  = (const float*)d_in[0];
  const float* Wl = (const float*)d_in[1];
  const float* fc = (const float*)d_in[2];
  const float* fq = (const float*)d_in[3];
  const int* src  = (const int*)d_in[4];
  const int* dst  = (const int*)d_in[5];
  float* out = (float*)d_out;

  char* ws = (char*)d_ws;
  float*  ft32 = (float*)(ws);                       // 25,600,000
  double* c64  = (double*)(ws + 25600000);           // 51,200,000
  float*  a3   = (float*)(ws + 25600000);            //   alias (after softedge): 12,800,000
  double* q64  = (double*)(ws + 76800000);           // 51,200,000
  double* cand = (double*)(ws + 76800000);           //   alias (after softedge): 25,600,000
  unsigned* A    = (unsigned*)(ws + 128000000);      // 200,004 (deg/cursor/offsets)
  unsigned* eidx = (unsigned*)(ws + 128200064);      // 3,200,000
  unsigned* hist = (unsigned*)(ws + 131400064);      // 4,096
  u64*    sel4  = (u64*)(ws + 131404160);            // 32
  unsigned* krem = (unsigned*)(ws + 131404192);      // 16
  unsigned* cnt  = (unsigned*)(ws + 131404208);      // 16
  unsigned* done = (unsigned*)(ws + 131404224);      // 16
  unsigned* ccnt = (unsigned*)(ws + 131404240);      // 16
  u64*    gsums = (u64*)(ws + 131404256);            // 64
  double* trd   = (double*)(ws + 131404320);         // 64

  double* abuf = (double*)d_out;                     // 25.6MB scratch inside out (32MB)

  hipMemsetAsync(A, 0, 200004, stream);
  hipMemsetAsync(hist, 0, 4096, stream);
  k_init<<<1, 64, 0, stream>>>(sel4, krem, cnt, done, ccnt, gsums);

  // CSR
  k_deg<<<(N_EDGES + 255) / 256, 256, 0, stream>>>(dst, A);
  k_scan<<<1, 1024, 0, stream>>>(A);
  k_fill<<<(N_EDGES + 255) / 256, 256, 0, stream>>>(dst, A, eidx);

  // GEMMs
  k_gemm32<<<(N_NODES + BM - 1) / BM, 256, 0, stream>>>(h, Wl, ft32);
  dim3 g64((N_NODES + 63) / 64, 4);
  k_gemm64<<<g64, 256, 0, stream>>>(h, fc, fq, c64, q64);

  // fused edge logits + softmax
  k_softedge<<<(N_NODES + 3) / 4, 256, 0, stream>>>(c64, q64, src, A, eidx, abuf);

  // exact 64-bit rank select: 2 global passes, compact, 6 parallel finish passes
  k_hp<<<1024, 256, 0, stream>>>(abuf, sel4, krem, cnt, hist, done, 0ull, 56);
  k_hp<<<1024, 256, 0, stream>>>(abuf, sel4, krem, cnt, hist, done,
                                 0xFF00000000000000ull, 48);
  k_compact<<<1024, 256, 0, stream>>>(abuf, sel4, ccnt, cand);
  for (int shift = 40; shift >= 0; shift -= 8)
    k_fin2<<<512, 256, 0, stream>>>(cand, ccnt, sel4, krem, cnt, hist, done, shift);

  // sums + a3 + ratio
  k_sums<<<2048, 256, 0, stream>>>(abuf, sel4, gsums, a3);
  k_ratio<<<1, 64, 0, stream>>>(sel4, cnt, gsums, trd);

  // output
  k_scatter2<<<(N_NODES + 3) / 4, 256, 0, stream>>>(ft32, src, A, eidx, a3, trd, out);
  k_mean<<<(N_NODES * DH + 255) / 256, 256, 0, stream>>>(ft32, out);
}

// Round 9
// 1051.017 us; speedup vs baseline: 1.0748x; 1.0748x over previous
//
#include <hip/hip_runtime.h>
#include <hip/hip_bf16.h>
#include <math.h>

#define N_NODES 50000
#define N_EDGES 800000
#define NH 4
#define DH 32
#define IN_DIM 256
#define OUTC 160
#define LS 570400     // int(0.713 * 800000) -> exactly 570400
#define RANK0 (LS - 1)
#define DEG_CAP 160   // max in-degree supported (Poisson(16); 160 = ~36 sigma)

typedef unsigned long long u64;
#define SC_FX 1099511627776.0   // 2^40 fixed-point scale

// ======== CSR build (A doubles as deg, cursor, and post-fill offsets[i+1]) ========
__global__ void k_deg(const int* __restrict__ dst, unsigned* __restrict__ A){
  int e = blockIdx.x * 256 + threadIdx.x;
  if (e < N_EDGES) atomicAdd(&A[dst[e]], 1u);
}

__global__ __launch_bounds__(1024) void k_scan(unsigned* __restrict__ A){
  __shared__ unsigned ps[1024];
  int t = threadIdx.x;
  const int CH = (N_NODES + 1023) / 1024;
  int base = t * CH;
  unsigned s = 0;
  for (int i = 0; i < CH; i++){ int n = base + i; if (n < N_NODES) s += A[n]; }
  ps[t] = s;
  __syncthreads();
  for (int off = 1; off < 1024; off <<= 1){
    unsigned v = (t >= off) ? ps[t - off] : 0;
    __syncthreads();
    ps[t] += v;
    __syncthreads();
  }
  unsigned ex = (t == 0) ? 0 : ps[t - 1];
  for (int i = 0; i < CH; i++){
    int n = base + i;
    if (n < N_NODES){ unsigned dv = A[n]; A[n] = ex; ex += dv; }
  }
}

__global__ void k_fill(const int* __restrict__ dst, unsigned* __restrict__ A,
                       unsigned* __restrict__ eidx){
  int e = blockIdx.x * 256 + threadIdx.x;
  if (e < N_EDGES) eidx[atomicAdd(&A[dst[e]], 1u)] = (unsigned)e;
}
// post-fill: A[d] == offsets[d+1]; node d range = [d? A[d-1]:0, A[d])

__global__ void k_init(u64* __restrict__ sel4, unsigned* __restrict__ krem,
                       unsigned* __restrict__ cnt, unsigned* __restrict__ done,
                       unsigned* __restrict__ ccnt, u64* __restrict__ gsums){
  int t = threadIdx.x;
  if (t < 4){ sel4[t] = 0; krem[t] = RANK0; cnt[t] = 0; ccnt[t] = 0; }
  if (t < 8) gsums[t] = 0;
  if (t == 0) done[0] = 0;
}

// ======== fp32 GEMM: ft32 = h * Wl^T ========
#define BM 128
#define BK 16
__global__ __launch_bounds__(256) void k_gemm32(const float* __restrict__ A,
                                                const float* __restrict__ Wl,
                                                float* __restrict__ C){
  __shared__ float As[BK][BM + 4];
  __shared__ float Bs[BK][128 + 4];
  int tid = threadIdx.x;
  int m0 = blockIdx.x * BM;
  int ty = tid / 16, tx = tid % 16;
  float acc[8][8];
  #pragma unroll
  for (int i = 0; i < 8; i++)
    #pragma unroll
    for (int j = 0; j < 8; j++) acc[i][j] = 0.f;

  for (int k0 = 0; k0 < IN_DIM; k0 += BK){
    #pragma unroll
    for (int i = 0; i < 2; i++){
      int s = tid * 2 + i;
      int row = s >> 2, c4 = s & 3;
      int r = m0 + row;
      float4 v = make_float4(0.f, 0.f, 0.f, 0.f);
      if (r < N_NODES) v = *(const float4*)&A[(size_t)r * IN_DIM + k0 + c4 * 4];
      As[c4 * 4 + 0][row] = v.x; As[c4 * 4 + 1][row] = v.y;
      As[c4 * 4 + 2][row] = v.z; As[c4 * 4 + 3][row] = v.w;
    }
    #pragma unroll
    for (int i = 0; i < 2; i++){
      int s = tid * 2 + i;
      int j = s >> 2, c4 = s & 3;          // Bs[k][j] = Wl[j][k0+k]
      float4 v = *(const float4*)&Wl[(size_t)j * IN_DIM + k0 + c4 * 4];
      Bs[c4 * 4 + 0][j] = v.x; Bs[c4 * 4 + 1][j] = v.y;
      Bs[c4 * 4 + 2][j] = v.z; Bs[c4 * 4 + 3][j] = v.w;
    }
    __syncthreads();
    #pragma unroll
    for (int kk = 0; kk < BK; kk++){
      float4 a0 = *(const float4*)&As[kk][ty * 4];
      float4 a1 = *(const float4*)&As[kk][64 + ty * 4];
      float4 b0 = *(const float4*)&Bs[kk][tx * 4];
      float4 b1 = *(const float4*)&Bs[kk][64 + tx * 4];
      float av[8] = {a0.x, a0.y, a0.z, a0.w, a1.x, a1.y, a1.z, a1.w};
      float bv[8] = {b0.x, b0.y, b0.z, b0.w, b1.x, b1.y, b1.z, b1.w};
      #pragma unroll
      for (int i = 0; i < 8; i++)
        #pragma unroll
        for (int j = 0; j < 8; j++)
          acc[i][j] = fmaf(av[i], bv[j], acc[i][j]);
    }
    __syncthreads();
  }
  #pragma unroll
  for (int i = 0; i < 8; i++){
    int r = m0 + ((i < 4) ? (ty * 4 + i) : (64 + ty * 4 + (i - 4)));
    if (r >= N_NODES) continue;
    *(float4*)&C[(size_t)r * 128 + tx * 4]      = make_float4(acc[i][0], acc[i][1], acc[i][2], acc[i][3]);
    *(float4*)&C[(size_t)r * 128 + 64 + tx * 4] = make_float4(acc[i][4], acc[i][5], acc[i][6], acc[i][7]);
  }
}

// ======== fp64 GEMM -> separate c64/q64 tables (bank-conflict-free B frags) ====
__global__ __launch_bounds__(256) void k_gemm64(const float* __restrict__ A,
                                                const float* __restrict__ fc,
                                                const float* __restrict__ fq,
                                                double* __restrict__ c64,
                                                double* __restrict__ q64){
  __shared__ double As[16][66];
  __shared__ double Bs[16][66];
  int tid = threadIdx.x;
  int m0 = blockIdx.x * 64;
  int n0 = blockIdx.y * 64;                 // 0..255 over [fc | fq]
  const float* Bsrc = (n0 < 128) ? fc : fq;
  int j0 = (n0 < 128) ? n0 : n0 - 128;
  double* Cp = (n0 < 128) ? c64 : q64;
  int ty = tid / 16, tx = tid % 16;
  double acc[4][4];
  #pragma unroll
  for (int i = 0; i < 4; i++)
    #pragma unroll
    for (int j = 0; j < 4; j++) acc[i][j] = 0.0;

  for (int k0 = 0; k0 < IN_DIM; k0 += 16){
    {
      int row = tid >> 2, c4 = tid & 3;
      int r = m0 + row;
      float4 v = make_float4(0.f, 0.f, 0.f, 0.f);
      if (r < N_NODES) v = *(const float4*)&A[(size_t)r * IN_DIM + k0 + c4 * 4];
      As[c4 * 4 + 0][row] = (double)v.x; As[c4 * 4 + 1][row] = (double)v.y;
      As[c4 * 4 + 2][row] = (double)v.z; As[c4 * 4 + 3][row] = (double)v.w;
    }
    {
      int kr = tid >> 4, c4 = tid & 15;
      float4 v = *(const float4*)&Bsrc[(size_t)(k0 + kr) * 128 + j0 + c4 * 4];
      Bs[kr][c4 * 4 + 0] = (double)v.x; Bs[kr][c4 * 4 + 1] = (double)v.y;
      Bs[kr][c4 * 4 + 2] = (double)v.z; Bs[kr][c4 * 4 + 3] = (double)v.w;
    }
    __syncthreads();
    #pragma unroll
    for (int kk = 0; kk < 16; kk++){
      double a[4], b[4];
      #pragma unroll
      for (int i = 0; i < 4; i++) a[i] = As[kk][ty * 4 + i];
      // strided B fragment: banks (2*tx)%32 -> 16 distinct banks, conflict-free
      #pragma unroll
      for (int j = 0; j < 4; j++) b[j] = Bs[kk][tx + 16 * j];
      #pragma unroll
      for (int i = 0; i < 4; i++)
        #pragma unroll
        for (int j = 0; j < 4; j++)
          acc[i][j] = fma(a[i], b[j], acc[i][j]);
    }
    __syncthreads();
  }
  #pragma unroll
  for (int i = 0; i < 4; i++){
    int r = m0 + ty * 4 + i;
    if (r >= N_NODES) continue;
    double* p = &Cp[(size_t)r * 128 + j0];
    #pragma unroll
    for (int j = 0; j < 4; j++) p[tx + 16 * j] = acc[i][j];   // coalesced 128B/16 lanes
  }
}

// ======== fused edge logits + exact softmax (wave per dst, CSR order) ========
__global__ __launch_bounds__(256) void k_softedge(const double* __restrict__ c64,
    const double* __restrict__ q64, const int* __restrict__ src,
    const unsigned* __restrict__ A, const unsigned* __restrict__ eidx,
    double* __restrict__ abuf){
  __shared__ double lds_a[4][DEG_CAP * 4];
  int d = blockIdx.x * 4 + (threadIdx.x >> 6);
  int t = threadIdx.x & 63;
  int wv = threadIdx.x >> 6;
  if (d >= N_NODES) return;
  unsigned k0 = d ? A[d - 1] : 0u, k1 = A[d];
  if (k0 == k1) return;
  double2 c = *(const double2*)&c64[(size_t)d * 128 + t * 2];
  double m = -1.0e300;
  int sn = src[eidx[k0]];
  double2 qn = *(const double2*)&q64[(size_t)sn * 128 + t * 2];
  for (unsigned k = k0; k < k1; k++){
    double2 q = qn;
    if (k + 1 < k1){
      int s2 = src[eidx[k + 1]];
      qn = *(const double2*)&q64[(size_t)s2 * 128 + t * 2];
    }
    double val = (q.x - c.x) * c.x + (q.y - c.y) * c.y;
    val += __shfl_xor(val, 1);
    val += __shfl_xor(val, 2);
    val += __shfl_xor(val, 4);
    val += __shfl_xor(val, 8);
    double a = (val > 0.0) ? val : expm1(val);   // ELU (f64)
    m = fmax(m, a);
    if ((t & 15) == 0) lds_a[wv][(k - k0) * 4 + (t >> 4)] = a;
  }
  double mm = __shfl(m, (t & 3) * 16);
  unsigned nj = (k1 - k0) * 4;
  long long sfx = 0;
  for (unsigned jj = t; jj < nj; jj += 64){
    double ex = exp(lds_a[wv][jj] - mm);         // jj%4 == t%4 (64%4==0)
    lds_a[wv][jj] = ex;
    sfx += llrint(ex * SC_FX);
  }
  #pragma unroll
  for (int msk = 4; msk < 64; msk <<= 1) sfx += __shfl_xor(sfx, msk);
  double sd = (double)sfx * (1.0 / SC_FX);
  for (unsigned jj = t; jj < nj; jj += 64)
    abuf[(size_t)k0 * 4 + jj] = lds_a[wv][jj] / sd;
}

// ======== radix select: hist+pick fused (last-block ticket), full array ========
__global__ __launch_bounds__(256) void k_hp(const double* __restrict__ attn,
    u64* __restrict__ sel4, unsigned* __restrict__ krem, unsigned* __restrict__ cnt,
    unsigned* __restrict__ hist, unsigned* __restrict__ done, u64 maskHi, int shift){
  __shared__ unsigned lh[1024];
  __shared__ unsigned ticket;
  for (int j = threadIdx.x; j < 1024; j += 256) lh[j] = 0;
  __syncthreads();
  int i0 = blockIdx.x * 256 + threadIdx.x;
  int hh = i0 & 3;
  u64 sel = sel4[hh] & maskHi;
  const int total = N_EDGES * 4;
  for (int i = i0; i < total; i += gridDim.x * 256){
    u64 u = (u64)__double_as_longlong(attn[i]);
    if ((u & maskHi) == sel)
      atomicAdd(&lh[hh * 256 + (unsigned)((u >> shift) & 255u)], 1u);
  }
  __syncthreads();
  for (int j = threadIdx.x; j < 1024; j += 256)
    if (lh[j]) atomicAdd(&hist[j], lh[j]);
  __threadfence();
  if (threadIdx.x == 0) ticket = atomicAdd(done, 1u);
  __syncthreads();
  if (ticket == gridDim.x - 1){
    __threadfence();
    for (int j = threadIdx.x; j < 1024; j += 256){ lh[j] = hist[j]; hist[j] = 0; }
    __syncthreads();
    if (threadIdx.x < 4){
      int t = threadIdx.x;
      unsigned kr = krem[t], cum = 0, b = 0;
      for (; b < 256; b++){
        unsigned c2 = lh[t * 256 + b];
        if (kr < cum + c2) break;
        cum += c2;
      }
      sel4[t] |= ((u64)b) << shift;
      krem[t] = kr - cum;
      cnt[t] += cum;
    }
    if (threadIdx.x == 0) *done = 0;
  }
}

// ======== compact candidates matching top-16 bits (two-level allocation) ========
__global__ __launch_bounds__(256) void k_compact(const double* __restrict__ attn,
    const u64* __restrict__ sel4, unsigned* __restrict__ ccnt,
    double* __restrict__ cand){
  __shared__ unsigned lcnt[4];
  __shared__ unsigned lbase[4];
  int t = threadIdx.x;
  if (t < 4) lcnt[t] = 0;
  __syncthreads();
  int i0 = blockIdx.x * 256 + t;
  int hh = i0 & 3;
  u64 sel = sel4[hh] & 0xFFFF000000000000ull;
  const int total = N_EDGES * 4;
  unsigned mc = 0;
  for (int i = i0; i < total; i += gridDim.x * 256){
    u64 u = (u64)__double_as_longlong(attn[i]);
    if ((u & 0xFFFF000000000000ull) == sel) mc++;
  }
  unsigned my_local = mc ? atomicAdd(&lcnt[hh], mc) : 0u;
  __syncthreads();
  if (t < 4) lbase[t] = lcnt[t] ? atomicAdd(&ccnt[t], lcnt[t]) : 0u;
  __syncthreads();
  if (mc == 0) return;
  unsigned pos = lbase[hh] + my_local;
  double* cp = cand + (size_t)hh * N_EDGES;
  for (int i = i0; i < total; i += gridDim.x * 256){
    double v = attn[i];
    u64 u = (u64)__double_as_longlong(v);
    if ((u & 0xFFFF000000000000ull) == sel) cp[pos++] = v;
  }
}

// ======== one radix pass over compacted candidates (multi-block, ticket pick) ====
__global__ __launch_bounds__(256) void k_fin2(const double* __restrict__ cand,
    const unsigned* __restrict__ ccnt, u64* __restrict__ sel4,
    unsigned* __restrict__ krem, unsigned* __restrict__ cnt,
    unsigned* __restrict__ hist, unsigned* __restrict__ done, int shift){
  __shared__ unsigned lh[256];
  __shared__ unsigned ticket;
  int t = threadIdx.x;
  lh[t] = 0;
  __syncthreads();
  int h = blockIdx.x & 3;                    // 4-way head split
  int bidx = blockIdx.x >> 2;
  int bph = gridDim.x >> 2;                  // blocks per head
  u64 maskHi = ~((1ull << (shift + 8)) - 1);
  u64 sel = sel4[h] & maskHi;
  unsigned n = ccnt[h];
  const double* cp = cand + (size_t)h * N_EDGES;
  for (unsigned i = bidx * 256 + t; i < n; i += bph * 256){
    u64 u = (u64)__double_as_longlong(cp[i]);
    if ((u & maskHi) == sel) atomicAdd(&lh[(unsigned)((u >> shift) & 255u)], 1u);
  }
  __syncthreads();
  if (lh[t]) atomicAdd(&hist[h * 256 + t], lh[t]);
  __threadfence();
  if (t == 0) ticket = atomicAdd(done, 1u);
  __syncthreads();
  if (ticket == gridDim.x - 1){
    __threadfence();
    __shared__ unsigned fh[1024];
    for (int j = t; j < 1024; j += 256){ fh[j] = hist[j]; hist[j] = 0; }
    __syncthreads();
    if (t < 4){
      unsigned kr = krem[t], cum = 0, b = 0;
      for (; b < 256; b++){
        unsigned c2 = fh[t * 256 + b];
        if (kr < cum + c2) break;
        cum += c2;
      }
      sel4[t] |= ((u64)b) << shift;
      krem[t] = kr - cum;
      cnt[t] += cum;
    }
    if (t == 0) *done = 0;
  }
}

// ======== sums below/above thd + a3 (f32, exact-cut applied) ========
__global__ __launch_bounds__(256) void k_sums(const double* __restrict__ attn,
    const u64* __restrict__ sel4, u64* __restrict__ gsums, float* __restrict__ a3){
  int t = threadIdx.x;
  int i0 = blockIdx.x * 256 + t;
  int hh = t & 3;
  double thd = __longlong_as_double((long long)sel4[hh]);
  double al = 0.0, ag = 0.0;
  const int total = N_EDGES * 4;
  for (int i = i0; i < total; i += gridDim.x * 256){
    double v = attn[i];
    if (v < thd){ al += v; a3[i] = 0.f; }
    else        { ag += v; a3[i] = (float)v; }
  }
  long long ql = llrint(al * SC_FX);
  long long qg = llrint(ag * SC_FX);
  #pragma unroll
  for (int m = 4; m < 64; m <<= 1){
    ql += __shfl_xor(ql, m);
    qg += __shfl_xor(qg, m);
  }
  __shared__ long long sl[16], sg[16];
  int wv = t >> 6;
  if ((t & 63) < 4){ sl[wv * 4 + hh] = ql; sg[wv * 4 + hh] = qg; }
  __syncthreads();
  if (t < 4){
    long long a = sl[t] + sl[4 + t] + sl[8 + t] + sl[12 + t];
    long long b = sg[t] + sg[4 + t] + sg[8 + t] + sg[12 + t];
    if (a) atomicAdd(&gsums[t],     (u64)a);
    if (b) atomicAdd(&gsums[4 + t], (u64)b);
  }
}

__global__ void k_ratio(const u64* __restrict__ sel4, const unsigned* __restrict__ cnt,
                        const u64* __restrict__ gsums, double* __restrict__ trd){
  int t = threadIdx.x;
  if (t < 4){
    double thd = __longlong_as_double((long long)sel4[t]);
    double sless = (double)gsums[t]     * (1.0 / SC_FX);
    double sge   = (double)gsums[4 + t] * (1.0 / SC_FX);
    double topk  = sless + (double)(LS - (int)cnt[t]) * thd;
    trd[t] = thd;
    trd[4 + t] = (sge + topk) / sge;
  }
}

// ======== CSR gather-scatter (wave per dst, int64 fixed-point registers) ========
__global__ __launch_bounds__(256) void k_scatter2(const float* __restrict__ ft,
    const int* __restrict__ src, const unsigned* __restrict__ A,
    const unsigned* __restrict__ eidx, const float* __restrict__ a3,
    const double* __restrict__ trd, float* __restrict__ out){
  int d = blockIdx.x * 4 + (threadIdx.x >> 6);
  int t = threadIdx.x & 63;
  if (d >= N_NODES) return;
  int hh = t >> 4;
  double ratio = trd[4 + hh];
  unsigned k0 = d ? A[d - 1] : 0u, k1 = A[d];
  long long acc0 = 0, acc1 = 0;
  float wn = (k0 < k1) ? a3[(size_t)k0 * 4 + hh] : 0.f;
  unsigned en = (k0 < k1) ? eidx[k0] : 0u;
  for (unsigned k = k0; k < k1; k++){
    float w = wn;
    unsigned e = en;
    if (k + 1 < k1){ wn = a3[(size_t)(k + 1) * 4 + hh]; en = eidx[k + 1]; }
    if (__ballot(w != 0.f) == 0ull) continue;    // ~71% of edges dropped
    if (w != 0.f){
      int s = src[e];
      float2 f = *(const float2*)&ft[(size_t)s * 128 + t * 2];
      double a3r = (double)w * ratio;
      acc0 += llrint(a3r * (double)f.x * SC_FX);
      acc1 += llrint(a3r * (double)f.y * SC_FX);
    }
  }
  float* p = &out[(size_t)d * OUTC + t * 2];
  p[0] = (float)((double)acc0 * (1.0 / SC_FX));
  p[1] = (float)((double)acc1 * (1.0 / SC_FX));
}

// ======== head-mean (runs last) ========
__global__ void k_mean(const float* __restrict__ ft, float* __restrict__ out){
  int i = blockIdx.x * 256 + threadIdx.x;
  if (i >= N_NODES * DH) return;
  int n = i / DH, dd = i % DH;
  const float* p = ft + (size_t)n * 128;
  out[(size_t)n * OUTC + 128 + dd] = 0.25f * (p[dd] + p[32 + dd] + p[64 + dd] + p[96 + dd]);
}

extern "C" void kernel_launch(void* const* d_in, const int* in_sizes, int n_in,
                              void* d_out, int out_size, void* d_ws, size_t ws_size,
                              hipStream_t stream){
  const float* h  = (const float*)d_in[0];
  const float* Wl = (const float*)d_in[1];
  const float* fc = (const float*)d_in[2];
  const float* fq = (const float*)d_in[3];
  const int* src  = (const int*)d_in[4];
  const int* dst  = (const int*)d_in[5];
  float* out = (float*)d_out;

  char* ws = (char*)d_ws;
  float*  ft32 = (float*)(ws);                       // 25,600,000
  double* c64  = (double*)(ws + 25600000);           // 51,200,000
  float*  a3   = (float*)(ws + 25600000);            //   alias (after softedge): 12,800,000
  double* q64  = (double*)(ws + 76800000);           // 51,200,000
  double* cand = (double*)(ws + 76800000);           //   alias (after softedge): 25,600,000
  unsigned* A    = (unsigned*)(ws + 128000000);      // 200,004 (deg/cursor/offsets)
  unsigned* eidx = (unsigned*)(ws + 128200064);      // 3,200,000
  unsigned* hist = (unsigned*)(ws + 131400064);      // 4,096
  u64*    sel4  = (u64*)(ws + 131404160);            // 32
  unsigned* krem = (unsigned*)(ws + 131404192);      // 16
  unsigned* cnt  = (unsigned*)(ws + 131404208);      // 16
  unsigned* done = (unsigned*)(ws + 131404224);      // 16
  unsigned* ccnt = (unsigned*)(ws + 131404240);      // 16
  u64*    gsums = (u64*)(ws + 131404256);            // 64
  double* trd   = (double*)(ws + 131404320);         // 64

  double* abuf = (double*)d_out;                     // 25.6MB scratch inside out (32MB)

  hipMemsetAsync(A, 0, 200004, stream);
  hipMemsetAsync(hist, 0, 4096, stream);
  k_init<<<1, 64, 0, stream>>>(sel4, krem, cnt, done, ccnt, gsums);

  // CSR
  k_deg<<<(N_EDGES + 255) / 256, 256, 0, stream>>>(dst, A);
  k_scan<<<1, 1024, 0, stream>>>(A);
  k_fill<<<(N_EDGES + 255) / 256, 256, 0, stream>>>(dst, A, eidx);

  // GEMMs
  k_gemm32<<<(N_NODES + BM - 1) / BM, 256, 0, stream>>>(h, Wl, ft32);
  dim3 g64((N_NODES + 63) / 64, 4);
  k_gemm64<<<g64, 256, 0, stream>>>(h, fc, fq, c64, q64);

  // fused edge logits + softmax
  k_softedge<<<(N_NODES + 3) / 4, 256, 0, stream>>>(c64, q64, src, A, eidx, abuf);

  // exact 64-bit rank select: 2 global passes, compact, 6 parallel finish passes
  k_hp<<<1024, 256, 0, stream>>>(abuf, sel4, krem, cnt, hist, done, 0ull, 56);
  k_hp<<<1024, 256, 0, stream>>>(abuf, sel4, krem, cnt, hist, done,
                                 0xFF00000000000000ull, 48);
  k_compact<<<1024, 256, 0, stream>>>(abuf, sel4, ccnt, cand);
  for (int shift = 40; shift >= 0; shift -= 8)
    k_fin2<<<256, 256, 0, stream>>>(cand, ccnt, sel4, krem, cnt, hist, done, shift);

  // sums + a3 + ratio
  k_sums<<<2048, 256, 0, stream>>>(abuf, sel4, gsums, a3);
  k_ratio<<<1, 64, 0, stream>>>(sel4, cnt, gsums, trd);

  // output
  k_scatter2<<<(N_NODES + 3) / 4, 256, 0, stream>>>(ft32, src, A, eidx, a3, trd, out);
  k_mean<<<(N_NODES * DH + 255) / 256, 256, 0, stream>>>(ft32, out);
}

// Round 11
// 1010.511 us; speedup vs baseline: 1.1178x; 1.0401x over previous
//
#include <hip/hip_runtime.h>
#include <hip/hip_bf16.h>
#include <math.h>

#define N_NODES 50000
#define N_EDGES 800000
#define NH 4
#define DH 32
#define IN_DIM 256
#define OUTC 160
#define LS 570400     // int(0.713 * 800000) -> exactly 570400
#define RANK0 (LS - 1)
#define DEG_CAP 160   // max in-degree supported (Poisson(16); 160 = ~36 sigma)

typedef unsigned long long u64;
typedef double f64x4 __attribute__((ext_vector_type(4)));
#define SC_FX 1099511627776.0   // 2^40 fixed-point scale

// ======== CSR build (A doubles as deg, cursor, and post-fill offsets[i+1]) ========
__global__ void k_deg(const int* __restrict__ dst, unsigned* __restrict__ A){
  int e = blockIdx.x * 256 + threadIdx.x;
  if (e < N_EDGES) atomicAdd(&A[dst[e]], 1u);
}

__global__ __launch_bounds__(1024) void k_scan(unsigned* __restrict__ A){
  __shared__ unsigned ps[1024];
  int t = threadIdx.x;
  const int CH = (N_NODES + 1023) / 1024;
  int base = t * CH;
  unsigned s = 0;
  for (int i = 0; i < CH; i++){ int n = base + i; if (n < N_NODES) s += A[n]; }
  ps[t] = s;
  __syncthreads();
  for (int off = 1; off < 1024; off <<= 1){
    unsigned v = (t >= off) ? ps[t - off] : 0;
    __syncthreads();
    ps[t] += v;
    __syncthreads();
  }
  unsigned ex = (t == 0) ? 0 : ps[t - 1];
  for (int i = 0; i < CH; i++){
    int n = base + i;
    if (n < N_NODES){ unsigned dv = A[n]; A[n] = ex; ex += dv; }
  }
}

__global__ void k_fill(const int* __restrict__ dst, unsigned* __restrict__ A,
                       unsigned* __restrict__ eidx){
  int e = blockIdx.x * 256 + threadIdx.x;
  if (e < N_EDGES) eidx[atomicAdd(&A[dst[e]], 1u)] = (unsigned)e;
}
// post-fill: A[d] == offsets[d+1]; node d range = [d? A[d-1]:0, A[d])

__global__ void k_init(u64* __restrict__ sel4, unsigned* __restrict__ krem,
                       unsigned* __restrict__ cnt, unsigned* __restrict__ done,
                       unsigned* __restrict__ ccnt, u64* __restrict__ gsums){
  int t = threadIdx.x;
  if (t < 4){ sel4[t] = 0; krem[t] = RANK0; cnt[t] = 0; ccnt[t] = 0; }
  if (t < 8) gsums[t] = 0;
  if (t == 0) done[0] = 0;
}

// ======== probe the f64 MFMA D-layout (deterministic HW property) ========
// A[m][k]=m, B=1 -> D[m][n]=4m ; A=1, B[k][n]=n -> D[m][n]=4n.
// lut[l*4+r] = row of (lane l, reg r); lut[256 + l*4+r] = col.
__global__ void k_probe(int* __restrict__ lut){
  int l = threadIdx.x & 63;
  f64x4 z = {0.0, 0.0, 0.0, 0.0};
  f64x4 dm = __builtin_amdgcn_mfma_f64_16x16x4f64((double)(l & 15), 1.0, z, 0, 0, 0);
  f64x4 dn = __builtin_amdgcn_mfma_f64_16x16x4f64(1.0, (double)(l & 15), z, 0, 0, 0);
  if (threadIdx.x < 64){
    #pragma unroll
    for (int r = 0; r < 4; r++){
      lut[l * 4 + r]       = (int)(dm[r] * 0.25 + 0.5);
      lut[256 + l * 4 + r] = (int)(dn[r] * 0.25 + 0.5);
    }
  }
}

// ======== fp32 GEMM: ft32 = h * Wl^T ========
#define BM 128
#define BK 16
__global__ __launch_bounds__(256) void k_gemm32(const float* __restrict__ A,
                                                const float* __restrict__ Wl,
                                                float* __restrict__ C){
  __shared__ float As[BK][BM + 4];
  __shared__ float Bs[BK][128 + 4];
  int tid = threadIdx.x;
  int m0 = blockIdx.x * BM;
  int ty = tid / 16, tx = tid % 16;
  float acc[8][8];
  #pragma unroll
  for (int i = 0; i < 8; i++)
    #pragma unroll
    for (int j = 0; j < 8; j++) acc[i][j] = 0.f;

  for (int k0 = 0; k0 < IN_DIM; k0 += BK){
    #pragma unroll
    for (int i = 0; i < 2; i++){
      int s = tid * 2 + i;
      int row = s >> 2, c4 = s & 3;
      int r = m0 + row;
      float4 v = make_float4(0.f, 0.f, 0.f, 0.f);
      if (r < N_NODES) v = *(const float4*)&A[(size_t)r * IN_DIM + k0 + c4 * 4];
      As[c4 * 4 + 0][row] = v.x; As[c4 * 4 + 1][row] = v.y;
      As[c4 * 4 + 2][row] = v.z; As[c4 * 4 + 3][row] = v.w;
    }
    #pragma unroll
    for (int i = 0; i < 2; i++){
      int s = tid * 2 + i;
      int j = s >> 2, c4 = s & 3;          // Bs[k][j] = Wl[j][k0+k]
      float4 v = *(const float4*)&Wl[(size_t)j * IN_DIM + k0 + c4 * 4];
      Bs[c4 * 4 + 0][j] = v.x; Bs[c4 * 4 + 1][j] = v.y;
      Bs[c4 * 4 + 2][j] = v.z; Bs[c4 * 4 + 3][j] = v.w;
    }
    __syncthreads();
    #pragma unroll
    for (int kk = 0; kk < BK; kk++){
      float4 a0 = *(const float4*)&As[kk][ty * 4];
      float4 a1 = *(const float4*)&As[kk][64 + ty * 4];
      float4 b0 = *(const float4*)&Bs[kk][tx * 4];
      float4 b1 = *(const float4*)&Bs[kk][64 + tx * 4];
      float av[8] = {a0.x, a0.y, a0.z, a0.w, a1.x, a1.y, a1.z, a1.w};
      float bv[8] = {b0.x, b0.y, b0.z, b0.w, b1.x, b1.y, b1.z, b1.w};
      #pragma unroll
      for (int i = 0; i < 8; i++)
        #pragma unroll
        for (int j = 0; j < 8; j++)
          acc[i][j] = fmaf(av[i], bv[j], acc[i][j]);
    }
    __syncthreads();
  }
  #pragma unroll
  for (int i = 0; i < 8; i++){
    int r = m0 + ((i < 4) ? (ty * 4 + i) : (64 + ty * 4 + (i - 4)));
    if (r >= N_NODES) continue;
    *(float4*)&C[(size_t)r * 128 + tx * 4]      = make_float4(acc[i][0], acc[i][1], acc[i][2], acc[i][3]);
    *(float4*)&C[(size_t)r * 128 + 64 + tx * 4] = make_float4(acc[i][4], acc[i][5], acc[i][6], acc[i][7]);
  }
}

// ======== fp64 GEMM via v_mfma_f64_16x16x4 with probed D layout ========
// A feed: lane l holds A[m=l&15][k=l>>4]; B feed: B[k=l>>4][n=l&15] (canonical).
// D writeback goes through the probed (row,col) LUT -> correct for any permutation.
__global__ __launch_bounds__(256) void k_gemm64(const float* __restrict__ A,
                                                const float* __restrict__ fc,
                                                const float* __restrict__ fq,
                                                const int* __restrict__ lut,
                                                double* __restrict__ c64,
                                                double* __restrict__ q64){
  __shared__ double As[16][68];
  __shared__ double Bs[16][68];
  int tid = threadIdx.x;
  int m0 = blockIdx.x * 64;
  int n0 = blockIdx.y * 64;                 // 0..255 over [fc | fq]
  const float* Bsrc = (n0 < 128) ? fc : fq;
  int j0 = (n0 < 128) ? n0 : n0 - 128;
  double* Cp = (n0 < 128) ? c64 : q64;
  int w = tid >> 6, l = tid & 63;
  int lr = l & 15, lk = l >> 4;
  int mr[4], nc[4];
  #pragma unroll
  for (int i = 0; i < 4; i++){ mr[i] = lut[l * 4 + i]; nc[i] = lut[256 + l * 4 + i]; }
  f64x4 acc[4];
  #pragma unroll
  for (int nt = 0; nt < 4; nt++) acc[nt] = (f64x4){0.0, 0.0, 0.0, 0.0};

  for (int k0 = 0; k0 < IN_DIM; k0 += 16){
    { // stage A: 64 rows x 16 k (f32 -> f64, transposed to As[k][row])
      int row = tid >> 2, c4 = tid & 3;
      int r = m0 + row;
      float4 v = make_float4(0.f, 0.f, 0.f, 0.f);
      if (r < N_NODES) v = *(const float4*)&A[(size_t)r * IN_DIM + k0 + c4 * 4];
      As[c4 * 4 + 0][row] = (double)v.x; As[c4 * 4 + 1][row] = (double)v.y;
      As[c4 * 4 + 2][row] = (double)v.z; As[c4 * 4 + 3][row] = (double)v.w;
    }
    { // stage B: 16 k x 64 cols
      int kr = tid >> 4, c4 = tid & 15;
      float4 v = *(const float4*)&Bsrc[(size_t)(k0 + kr) * 128 + j0 + c4 * 4];
      Bs[kr][c4 * 4 + 0] = (double)v.x; Bs[kr][c4 * 4 + 1] = (double)v.y;
      Bs[kr][c4 * 4 + 2] = (double)v.z; Bs[kr][c4 * 4 + 3] = (double)v.w;
    }
    __syncthreads();
    #pragma unroll
    for (int kk4 = 0; kk4 < 4; kk4++){
      int kb = kk4 * 4 + lk;
      double a = As[kb][w * 16 + lr];
      #pragma unroll
      for (int nt = 0; nt < 4; nt++){
        double b = Bs[kb][nt * 16 + lr];
        acc[nt] = __builtin_amdgcn_mfma_f64_16x16x4f64(a, b, acc[nt], 0, 0, 0);
      }
    }
    __syncthreads();
  }
  #pragma unroll
  for (int nt = 0; nt < 4; nt++){
    #pragma unroll
    for (int i = 0; i < 4; i++){
      int r = m0 + w * 16 + mr[i];
      if (r < N_NODES) Cp[(size_t)r * 128 + j0 + nt * 16 + nc[i]] = acc[nt][i];
    }
  }
}

// ======== fused edge logits + exact softmax (wave per dst, CSR order) ========
__global__ __launch_bounds__(256) void k_softedge(const double* __restrict__ c64,
    const double* __restrict__ q64, const int* __restrict__ src,
    const unsigned* __restrict__ A, const unsigned* __restrict__ eidx,
    double* __restrict__ abuf){
  __shared__ double lds_a[4][DEG_CAP * 4];
  int d = blockIdx.x * 4 + (threadIdx.x >> 6);
  int t = threadIdx.x & 63;
  int wv = threadIdx.x >> 6;
  if (d >= N_NODES) return;
  unsigned k0 = d ? A[d - 1] : 0u, k1 = A[d];
  if (k0 == k1) return;
  double2 c = *(const double2*)&c64[(size_t)d * 128 + t * 2];
  double m = -1.0e300;
  int sn = src[eidx[k0]];
  double2 qn = *(const double2*)&q64[(size_t)sn * 128 + t * 2];
  for (unsigned k = k0; k < k1; k++){
    double2 q = qn;
    if (k + 1 < k1){
      int s2 = src[eidx[k + 1]];
      qn = *(const double2*)&q64[(size_t)s2 * 128 + t * 2];
    }
    double val = (q.x - c.x) * c.x + (q.y - c.y) * c.y;
    val += __shfl_xor(val, 1);
    val += __shfl_xor(val, 2);
    val += __shfl_xor(val, 4);
    val += __shfl_xor(val, 8);
    double a = (val > 0.0) ? val : expm1(val);   // ELU (f64)
    m = fmax(m, a);
    if ((t & 15) == 0) lds_a[wv][(k - k0) * 4 + (t >> 4)] = a;
  }
  double mm = __shfl(m, (t & 3) * 16);
  unsigned nj = (k1 - k0) * 4;
  long long sfx = 0;
  for (unsigned jj = t; jj < nj; jj += 64){
    double ex = exp(lds_a[wv][jj] - mm);         // jj%4 == t%4 (64%4==0)
    lds_a[wv][jj] = ex;
    sfx += llrint(ex * SC_FX);
  }
  #pragma unroll
  for (int msk = 4; msk < 64; msk <<= 1) sfx += __shfl_xor(sfx, msk);
  double sd = (double)sfx * (1.0 / SC_FX);
  for (unsigned jj = t; jj < nj; jj += 64)
    abuf[(size_t)k0 * 4 + jj] = lds_a[wv][jj] / sd;
}

// ======== radix select: hist+pick fused (last-block ticket), full array ========
__global__ __launch_bounds__(256) void k_hp(const double* __restrict__ attn,
    u64* __restrict__ sel4, unsigned* __restrict__ krem, unsigned* __restrict__ cnt,
    unsigned* __restrict__ hist, unsigned* __restrict__ done, u64 maskHi, int shift){
  __shared__ unsigned lh[1024];
  __shared__ unsigned ticket;
  for (int j = threadIdx.x; j < 1024; j += 256) lh[j] = 0;
  __syncthreads();
  int i0 = blockIdx.x * 256 + threadIdx.x;
  int hh = i0 & 3;
  u64 sel = sel4[hh] & maskHi;
  const int total = N_EDGES * 4;
  for (int i = i0; i < total; i += gridDim.x * 256){
    u64 u = (u64)__double_as_longlong(attn[i]);
    if ((u & maskHi) == sel)
      atomicAdd(&lh[hh * 256 + (unsigned)((u >> shift) & 255u)], 1u);
  }
  __syncthreads();
  for (int j = threadIdx.x; j < 1024; j += 256)
    if (lh[j]) atomicAdd(&hist[j], lh[j]);
  __threadfence();
  if (threadIdx.x == 0) ticket = atomicAdd(done, 1u);
  __syncthreads();
  if (ticket == gridDim.x - 1){
    __threadfence();
    for (int j = threadIdx.x; j < 1024; j += 256){ lh[j] = hist[j]; hist[j] = 0; }
    __syncthreads();
    if (threadIdx.x < 4){
      int t = threadIdx.x;
      unsigned kr = krem[t], cum = 0, b = 0;
      for (; b < 256; b++){
        unsigned c2 = lh[t * 256 + b];
        if (kr < cum + c2) break;
        cum += c2;
      }
      sel4[t] |= ((u64)b) << shift;
      krem[t] = kr - cum;
      cnt[t] += cum;
    }
    if (threadIdx.x == 0) *done = 0;
  }
}

// ======== compact candidates matching top-16 bits (two-level allocation) ========
__global__ __launch_bounds__(256) void k_compact(const double* __restrict__ attn,
    const u64* __restrict__ sel4, unsigned* __restrict__ ccnt,
    double* __restrict__ cand){
  __shared__ unsigned lcnt[4];
  __shared__ unsigned lbase[4];
  int t = threadIdx.x;
  if (t < 4) lcnt[t] = 0;
  __syncthreads();
  int i0 = blockIdx.x * 256 + t;
  int hh = i0 & 3;
  u64 sel = sel4[hh] & 0xFFFF000000000000ull;
  const int total = N_EDGES * 4;
  unsigned mc = 0;
  for (int i = i0; i < total; i += gridDim.x * 256){
    u64 u = (u64)__double_as_longlong(attn[i]);
    if ((u & 0xFFFF000000000000ull) == sel) mc++;
  }
  unsigned my_local = mc ? atomicAdd(&lcnt[hh], mc) : 0u;
  __syncthreads();
  if (t < 4) lbase[t] = lcnt[t] ? atomicAdd(&ccnt[t], lcnt[t]) : 0u;
  __syncthreads();
  if (mc == 0) return;
  unsigned pos = lbase[hh] + my_local;
  double* cp = cand + (size_t)hh * N_EDGES;
  for (int i = i0; i < total; i += gridDim.x * 256){
    double v = attn[i];
    u64 u = (u64)__double_as_longlong(v);
    if ((u & 0xFFFF000000000000ull) == sel) cp[pos++] = v;
  }
}

// ======== one radix pass over compacted candidates (multi-block, ticket pick) ====
__global__ __launch_bounds__(256) void k_fin2(const double* __restrict__ cand,
    const unsigned* __restrict__ ccnt, u64* __restrict__ sel4,
    unsigned* __restrict__ krem, unsigned* __restrict__ cnt,
    unsigned* __restrict__ hist, unsigned* __restrict__ done, int shift){
  __shared__ unsigned lh[256];
  __shared__ unsigned ticket;
  int t = threadIdx.x;
  lh[t] = 0;
  __syncthreads();
  int h = blockIdx.x & 3;                    // 4-way head split
  int bidx = blockIdx.x >> 2;
  int bph = gridDim.x >> 2;                  // blocks per head
  u64 maskHi = ~((1ull << (shift + 8)) - 1);
  u64 sel = sel4[h] & maskHi;
  unsigned n = ccnt[h];
  const double* cp = cand + (size_t)h * N_EDGES;
  for (unsigned i = bidx * 256 + t; i < n; i += bph * 256){
    u64 u = (u64)__double_as_longlong(cp[i]);
    if ((u & maskHi) == sel) atomicAdd(&lh[(unsigned)((u >> shift) & 255u)], 1u);
  }
  __syncthreads();
  if (lh[t]) atomicAdd(&hist[h * 256 + t], lh[t]);
  __threadfence();
  if (t == 0) ticket = atomicAdd(done, 1u);
  __syncthreads();
  if (ticket == gridDim.x - 1){
    __threadfence();
    __shared__ unsigned fh[1024];
    for (int j = t; j < 1024; j += 256){ fh[j] = hist[j]; hist[j] = 0; }
    __syncthreads();
    if (t < 4){
      unsigned kr = krem[t], cum = 0, b = 0;
      for (; b < 256; b++){
        unsigned c2 = fh[t * 256 + b];
        if (kr < cum + c2) break;
        cum += c2;
      }
      sel4[t] |= ((u64)b) << shift;
      krem[t] = kr - cum;
      cnt[t] += cum;
    }
    if (t == 0) *done = 0;
  }
}

// ======== sums below/above thd + a3 (f32, exact-cut applied) ========
__global__ __launch_bounds__(256) void k_sums(const double* __restrict__ attn,
    const u64* __restrict__ sel4, u64* __restrict__ gsums, float* __restrict__ a3){
  int t = threadIdx.x;
  int i0 = blockIdx.x * 256 + t;
  int hh = t & 3;
  double thd = __longlong_as_double((long long)sel4[hh]);
  double al = 0.0, ag = 0.0;
  const int total = N_EDGES * 4;
  for (int i = i0; i < total; i += gridDim.x * 256){
    double v = attn[i];
    if (v < thd){ al += v; a3[i] = 0.f; }
    else        { ag += v; a3[i] = (float)v; }
  }
  long long ql = llrint(al * SC_FX);
  long long qg = llrint(ag * SC_FX);
  #pragma unroll
  for (int m = 4; m < 64; m <<= 1){
    ql += __shfl_xor(ql, m);
    qg += __shfl_xor(qg, m);
  }
  __shared__ long long sl[16], sg[16];
  int wv = t >> 6;
  if ((t & 63) < 4){ sl[wv * 4 + hh] = ql; sg[wv * 4 + hh] = qg; }
  __syncthreads();
  if (t < 4){
    long long a = sl[t] + sl[4 + t] + sl[8 + t] + sl[12 + t];
    long long b = sg[t] + sg[4 + t] + sg[8 + t] + sg[12 + t];
    if (a) atomicAdd(&gsums[t],     (u64)a);
    if (b) atomicAdd(&gsums[4 + t], (u64)b);
  }
}

__global__ void k_ratio(const u64* __restrict__ sel4, const unsigned* __restrict__ cnt,
                        const u64* __restrict__ gsums, double* __restrict__ trd){
  int t = threadIdx.x;
  if (t < 4){
    double thd = __longlong_as_double((long long)sel4[t]);
    double sless = (double)gsums[t]     * (1.0 / SC_FX);
    double sge   = (double)gsums[4 + t] * (1.0 / SC_FX);
    double topk  = sless + (double)(LS - (int)cnt[t]) * thd;
    trd[t] = thd;
    trd[4 + t] = (sge + topk) / sge;
  }
}

// ======== CSR gather-scatter (wave per dst, int64 fixed-point registers) ========
__global__ __launch_bounds__(256) void k_scatter2(const float* __restrict__ ft,
    const int* __restrict__ src, const unsigned* __restrict__ A,
    const unsigned* __restrict__ eidx, const float* __restrict__ a3,
    const double* __restrict__ trd, float* __restrict__ out){
  int d = blockIdx.x * 4 + (threadIdx.x >> 6);
  int t = threadIdx.x & 63;
  if (d >= N_NODES) return;
  int hh = t >> 4;
  double ratio = trd[4 + hh];
  unsigned k0 = d ? A[d - 1] : 0u, k1 = A[d];
  long long acc0 = 0, acc1 = 0;
  float wn = (k0 < k1) ? a3[(size_t)k0 * 4 + hh] : 0.f;
  unsigned en = (k0 < k1) ? eidx[k0] : 0u;
  for (unsigned k = k0; k < k1; k++){
    float w = wn;
    unsigned e = en;
    if (k + 1 < k1){ wn = a3[(size_t)(k + 1) * 4 + hh]; en = eidx[k + 1]; }
    if (__ballot(w != 0.f) == 0ull) continue;    // ~71% of edges dropped
    if (w != 0.f){
      int s = src[e];
      float2 f = *(const float2*)&ft[(size_t)s * 128 + t * 2];
      double a3r = (double)w * ratio;
      acc0 += llrint(a3r * (double)f.x * SC_FX);
      acc1 += llrint(a3r * (double)f.y * SC_FX);
    }
  }
  float* p = &out[(size_t)d * OUTC + t * 2];
  p[0] = (float)((double)acc0 * (1.0 / SC_FX));
  p[1] = (float)((double)acc1 * (1.0 / SC_FX));
}

// ======== head-mean (runs last) ========
__global__ void k_mean(const float* __restrict__ ft, float* __restrict__ out){
  int i = blockIdx.x * 256 + threadIdx.x;
  if (i >= N_NODES * DH) return;
  int n = i / DH, dd = i % DH;
  const float* p = ft + (size_t)n * 128;
  out[(size_t)n * OUTC + 128 + dd] = 0.25f * (p[dd] + p[32 + dd] + p[64 + dd] + p[96 + dd]);
}

extern "C" void kernel_launch(void* const* d_in, const int* in_sizes, int n_in,
                              void* d_out, int out_size, void* d_ws, size_t ws_size,
                              hipStream_t stream){
  const float* h  = (const float*)d_in[0];
  const float* Wl = (const float*)d_in[1];
  const float* fc = (const float*)d_in[2];
  const float* fq = (const float*)d_in[3];
  const int* src  = (const int*)d_in[4];
  const int* dst  = (const int*)d_in[5];
  float* out = (float*)d_out;

  char* ws = (char*)d_ws;
  float*  ft32 = (float*)(ws);                       // 25,600,000
  double* c64  = (double*)(ws + 25600000);           // 51,200,000
  float*  a3   = (float*)(ws + 25600000);            //   alias (after softedge): 12,800,000
  double* q64  = (double*)(ws + 76800000);           // 51,200,000
  double* cand = (double*)(ws + 76800000);           //   alias (after softedge): 25,600,000
  unsigned* A    = (unsigned*)(ws + 128000000);      // 200,004 (deg/cursor/offsets)
  unsigned* eidx = (unsigned*)(ws + 128200064);      // 3,200,000
  unsigned* hist = (unsigned*)(ws + 131400064);      // 4,096
  u64*    sel4  = (u64*)(ws + 131404160);            // 32
  unsigned* krem = (unsigned*)(ws + 131404192);      // 16
  unsigned* cnt  = (unsigned*)(ws + 131404208);      // 16
  unsigned* done = (unsigned*)(ws + 131404224);      // 16
  unsigned* ccnt = (unsigned*)(ws + 131404240);      // 16
  u64*    gsums = (u64*)(ws + 131404256);            // 64
  double* trd   = (double*)(ws + 131404320);         // 64
  int*    lut   = (int*)(ws + 131404416);            // 2,048 (D-layout probe)

  double* abuf = (double*)d_out;                     // 25.6MB scratch inside out (32MB)

  hipMemsetAsync(A, 0, 200004, stream);
  hipMemsetAsync(hist, 0, 4096, stream);
  k_init<<<1, 64, 0, stream>>>(sel4, krem, cnt, done, ccnt, gsums);
  k_probe<<<1, 64, 0, stream>>>(lut);

  // CSR
  k_deg<<<(N_EDGES + 255) / 256, 256, 0, stream>>>(dst, A);
  k_scan<<<1, 1024, 0, stream>>>(A);
  k_fill<<<(N_EDGES + 255) / 256, 256, 0, stream>>>(dst, A, eidx);

  // GEMMs
  k_gemm32<<<(N_NODES + BM - 1) / BM, 256, 0, stream>>>(h, Wl, ft32);
  dim3 g64((N_NODES + 63) / 64, 4);
  k_gemm64<<<g64, 256, 0, stream>>>(h, fc, fq, lut, c64, q64);

  // fused edge logits + softmax
  k_softedge<<<(N_NODES + 3) / 4, 256, 0, stream>>>(c64, q64, src, A, eidx, abuf);

  // exact 64-bit rank select: 2 global passes, compact, 6 parallel finish passes
  k_hp<<<1024, 256, 0, stream>>>(abuf, sel4, krem, cnt, hist, done, 0ull, 56);
  k_hp<<<1024, 256, 0, stream>>>(abuf, sel4, krem, cnt, hist, done,
                                 0xFF00000000000000ull, 48);
  k_compact<<<1024, 256, 0, stream>>>(abuf, sel4, ccnt, cand);
  for (int shift = 40; shift >= 0; shift -= 8)
    k_fin2<<<256, 256, 0, stream>>>(cand, ccnt, sel4, krem, cnt, hist, done, shift);

  // sums + a3 + ratio
  k_sums<<<2048, 256, 0, stream>>>(abuf, sel4, gsums, a3);
  k_ratio<<<1, 64, 0, stream>>>(sel4, cnt, gsums, trd);

  // output
  k_scatter2<<<(N_NODES + 3) / 4, 256, 0, stream>>>(ft32, src, A, eidx, a3, trd, out);
  k_mean<<<(N_NODES * DH + 255) / 256, 256, 0, stream>>>(ft32, out);
}